// Round 5
// baseline (32459.937 us; speedup 1.0000x reference)
//
#include <hip/hip_runtime.h>
#include <cstdint>
#include <cstddef>

// Decoder (DA-RNN): B=512, T=256, E=D=256.
// Round 7: streamed weights + cross-barrier register prefetch (transient SSA,
// NOT persistent: R5/R6 proved the allocator spills persistent weight sets).
// 256 blocks x 512 threads, G=2 rows/block, launch_bounds(512,2) -> 256-VGPR cap.
// Four 16xhalf8 units A/B/C/D rotate through the 8 load-groups per step
// (WQx2, GWx4, PHx2); each group is issued ~one phase before consumption, so
// L2 latency hides under the previous phase's compute; barrier vmcnt drains
// then cost nothing. Peak ~3 units live (192 VGPR) + working. 4 barriers/step.
// All LDS h-reads wave-uniform broadcasts (conflict-free).

typedef _Float16 half8 __attribute__((ext_vector_type(8)));
typedef _Float16 half4v __attribute__((ext_vector_type(4)));
typedef _Float16 half2v __attribute__((ext_vector_type(2)));

__device__ __forceinline__ float rcpf_(float x) { return __builtin_amdgcn_rcpf(x); }
__device__ __forceinline__ float sigmoidf_(float x) { return rcpf_(1.f + __expf(-x)); }
__device__ __forceinline__ float tanhf_(float x) { return 1.f - 2.f * rcpf_(1.f + __expf(2.f * x)); }

#if defined(__has_builtin)
#if __has_builtin(__builtin_amdgcn_fdot2)
#define HAS_FDOT2 1
#endif
#endif
#ifndef HAS_FDOT2
#define HAS_FDOT2 0
#endif

__device__ __forceinline__ float fdot2_(half2v a, half2v b, float c) {
#if HAS_FDOT2
  return __builtin_amdgcn_fdot2(a, b, c, false);
#else
  return fmaf((float)a[0], (float)b[0], fmaf((float)a[1], (float)b[1], c));
#endif
}

__device__ __forceinline__ float dot8_(half8 w, half8 h, float acc) {
  acc = fdot2_(__builtin_shufflevector(w, w, 0, 1), __builtin_shufflevector(h, h, 0, 1), acc);
  acc = fdot2_(__builtin_shufflevector(w, w, 2, 3), __builtin_shufflevector(h, h, 2, 3), acc);
  acc = fdot2_(__builtin_shufflevector(w, w, 4, 5), __builtin_shufflevector(h, h, 4, 5), acc);
  acc = fdot2_(__builtin_shufflevector(w, w, 6, 7), __builtin_shufflevector(h, h, 6, 7), acc);
  return acc;
}

// ---------------- prep kernels (unchanged layouts) ----------------

// wT[e*256+f] = attn_w1[f*768 + 512 + e]   (transposed w1_enc, fp32)
__global__ void k_prep_wT(const float* __restrict__ w1, float* __restrict__ wT) {
  int id = blockIdx.x * 256 + threadIdx.x;
  int e = id >> 8, f = id & 255;
  wT[id] = w1[f * 768 + 512 + e];
}

// x -> fp16 (4 elems/thread), layout unchanged [b][t][e]
__global__ void k_prep_xh(const float* __restrict__ x, _Float16* __restrict__ xh) {
  int id = blockIdx.x * 256 + threadIdx.x;
  float4 v = reinterpret_cast<const float4*>(x)[id];
  half4v h;
  h[0] = (_Float16)v.x; h[1] = (_Float16)v.y; h[2] = (_Float16)v.z; h[3] = (_Float16)v.w;
  reinterpret_cast<half4v*>(xh)[id] = h;
}

// w1hcQ[(c*512 + t)*8 + m] = w1[e*768 + k], t = jk*256+e, k = jk*256 + c*8 + m,
// c in [0,32). Thread t of k_scan streams chunks c=0..31.
__global__ void k_prep_w1hcQ(const float* __restrict__ w1, _Float16* __restrict__ o) {
  int id = blockIdx.x * 256 + threadIdx.x;  // 131072 total
  int m = id & 7, t = (id >> 3) & 511, c = id >> 12;
  int e = t & 255, jk = t >> 8;
  int k = jk * 256 + c * 8 + m;
  o[id] = (_Float16)w1[e * 768 + k];
}

// whhG[(((jk2*16 + c)*4 + js)*256 + jo)*8 + m] = Whh[(js*256+jo)*256 + jk2*128 + c*8 + m]
// (thread (jk2,jo) streams chunks (c=0..15, js=0..3); outputs js*256+jo over
// k in [jk2*128, +128))
__global__ void k_prep_whhG(const float* __restrict__ whh, _Float16* __restrict__ o) {
  int id = blockIdx.x * 256 + threadIdx.x;  // 262144 total
  int m = id & 7, jo = (id >> 3) & 255, js = (id >> 11) & 3;
  int c = (id >> 13) & 15, jk2 = id >> 17;
  int j = js * 256 + jo, k = jk2 * 128 + c * 8 + m;
  o[id] = (_Float16)whh[j * 256 + k];
}

// xf[b*256+t] = sum_e x[b,t,e] * fcw[e]   (fp32)
__global__ __launch_bounds__(256) void k_xf(const float* __restrict__ x,
                                            const float* __restrict__ fcw,
                                            float* __restrict__ xf) {
  __shared__ float xl[16][256];
  __shared__ float fw[256];
  __shared__ float part[16][17];
  const int tid = threadIdx.x;
  const int m0 = blockIdx.x * 16;
  fw[tid] = fcw[tid];
#pragma unroll
  for (int r = 0; r < 16; ++r) xl[r][tid] = x[(size_t)(m0 + r) * 256 + tid];
  __syncthreads();
  int r = tid >> 4, p = tid & 15;
  float s = 0.f;
#pragma unroll
  for (int u = 0; u < 16; ++u) s = fmaf(xl[r][p * 16 + u], fw[p * 16 + u], s);
  part[r][p] = s;
  __syncthreads();
  if (tid < 16) {
    float t = 0.f;
#pragma unroll
    for (int p2 = 0; p2 < 16; ++p2) t += part[tid][p2];
    xf[m0 + tid] = t;
  }
}

// enc_proj GEMM + bias, store P=exp(2*encp) fp16 in layout [b][e/8][t][e%8]
__global__ __launch_bounds__(256) void k_encp(const float* __restrict__ x,
                                              const float* __restrict__ wT,
                                              const float* __restrict__ b1,
                                              _Float16* __restrict__ Ph2) {
  __shared__ __align__(16) float xl[16][256];
  const int tid = threadIdx.x;
  const int m0 = blockIdx.x * 16;
#pragma unroll
  for (int r = 0; r < 16; ++r) xl[r][tid] = x[(size_t)(m0 + r) * 256 + tid];
  __syncthreads();
  float acc[16];
#pragma unroll
  for (int r = 0; r < 16; ++r) acc[r] = 0.f;
  for (int e = 0; e < 256; e += 4) {
    float w0 = wT[(e + 0) * 256 + tid];
    float w1_ = wT[(e + 1) * 256 + tid];
    float w2_ = wT[(e + 2) * 256 + tid];
    float w3_ = wT[(e + 3) * 256 + tid];
#pragma unroll
    for (int r = 0; r < 16; ++r) {
      float4 xv = *reinterpret_cast<const float4*>(&xl[r][e]);
      acc[r] = fmaf(xv.x, w0, acc[r]);
      acc[r] = fmaf(xv.y, w1_, acc[r]);
      acc[r] = fmaf(xv.z, w2_, acc[r]);
      acc[r] = fmaf(xv.w, w3_, acc[r]);
    }
  }
  float bb = b1[tid];
  const int e = tid;
#pragma unroll
  for (int r = 0; r < 16; ++r) {
    int m = m0 + r, b = m >> 8, t = m & 255;
    float p = __expf(2.f * (acc[r] + bb));
    Ph2[((size_t)(b * 32 + (e >> 3)) * 256 + t) * 8 + (e & 7)] = (_Float16)p;
  }
}

// ---------------- prefetch-unit machinery ----------------
#define UDECL(u) half8 u##0,u##1,u##2,u##3,u##4,u##5,u##6,u##7, \
                       u##8,u##9,u##10,u##11,u##12,u##13,u##14,u##15
#define ULOAD(u, base, stride, off) do { \
  u##0  = (base)[((off)+ 0)*(stride)]; u##1  = (base)[((off)+ 1)*(stride)]; \
  u##2  = (base)[((off)+ 2)*(stride)]; u##3  = (base)[((off)+ 3)*(stride)]; \
  u##4  = (base)[((off)+ 4)*(stride)]; u##5  = (base)[((off)+ 5)*(stride)]; \
  u##6  = (base)[((off)+ 6)*(stride)]; u##7  = (base)[((off)+ 7)*(stride)]; \
  u##8  = (base)[((off)+ 8)*(stride)]; u##9  = (base)[((off)+ 9)*(stride)]; \
  u##10 = (base)[((off)+10)*(stride)]; u##11 = (base)[((off)+11)*(stride)]; \
  u##12 = (base)[((off)+12)*(stride)]; u##13 = (base)[((off)+13)*(stride)]; \
  u##14 = (base)[((off)+14)*(stride)]; u##15 = (base)[((off)+15)*(stride)]; \
} while (0)

#define QD1(w, c) { half8 h0_ = hp0[c], h1_ = hp1[c]; \
  a0 = dot8_(w, h0_, a0); a1 = dot8_(w, h1_, a1); }
#define QDOTS(u, cb) do { \
  QD1(u##0,(cb)+0)  QD1(u##1,(cb)+1)  QD1(u##2,(cb)+2)  QD1(u##3,(cb)+3) \
  QD1(u##4,(cb)+4)  QD1(u##5,(cb)+5)  QD1(u##6,(cb)+6)  QD1(u##7,(cb)+7) \
  QD1(u##8,(cb)+8)  QD1(u##9,(cb)+9)  QD1(u##10,(cb)+10) QD1(u##11,(cb)+11) \
  QD1(u##12,(cb)+12) QD1(u##13,(cb)+13) QD1(u##14,(cb)+14) QD1(u##15,(cb)+15) \
} while (0)

#define GATES4(w0,w1,w2,w3,c) { half8 h0_ = hg0[c], h1_ = hg1[c]; \
  ac00 = dot8_(w0,h0_,ac00); ac10 = dot8_(w0,h1_,ac10); \
  ac01 = dot8_(w1,h0_,ac01); ac11 = dot8_(w1,h1_,ac11); \
  ac02 = dot8_(w2,h0_,ac02); ac12 = dot8_(w2,h1_,ac12); \
  ac03 = dot8_(w3,h0_,ac03); ac13 = dot8_(w3,h1_,ac13); }
#define GATES16(u, gb) do { \
  GATES4(u##0, u##1, u##2, u##3, (gb)+0) \
  GATES4(u##4, u##5, u##6, u##7, (gb)+1) \
  GATES4(u##8, u##9, u##10,u##11,(gb)+2) \
  GATES4(u##12,u##13,u##14,u##15,(gb)+3) \
} while (0)

#define SC1(pv, c) { \
  float4 qa = q4[2*(c)], wa = w4[2*(c)]; \
  sacc0 = fmaf(wa.x, rcpf_(fmaf((float)pv[0], qa.x, 1.f)), sacc0); \
  sacc1 = fmaf(wa.y, rcpf_(fmaf((float)pv[1], qa.y, 1.f)), sacc1); \
  sacc0 = fmaf(wa.z, rcpf_(fmaf((float)pv[2], qa.z, 1.f)), sacc0); \
  sacc1 = fmaf(wa.w, rcpf_(fmaf((float)pv[3], qa.w, 1.f)), sacc1); \
  float4 qb = q4[2*(c)+1], wb = w4[2*(c)+1]; \
  sacc0 = fmaf(wb.x, rcpf_(fmaf((float)pv[4], qb.x, 1.f)), sacc0); \
  sacc1 = fmaf(wb.y, rcpf_(fmaf((float)pv[5], qb.y, 1.f)), sacc1); \
  sacc0 = fmaf(wb.z, rcpf_(fmaf((float)pv[6], qb.z, 1.f)), sacc0); \
  sacc1 = fmaf(wb.w, rcpf_(fmaf((float)pv[7], qb.w, 1.f)), sacc1); }
#define SC16(u, cb) do { \
  SC1(u##0,(cb)+0)  SC1(u##1,(cb)+1)  SC1(u##2,(cb)+2)  SC1(u##3,(cb)+3) \
  SC1(u##4,(cb)+4)  SC1(u##5,(cb)+5)  SC1(u##6,(cb)+6)  SC1(u##7,(cb)+7) \
  SC1(u##8,(cb)+8)  SC1(u##9,(cb)+9)  SC1(u##10,(cb)+10) SC1(u##11,(cb)+11) \
  SC1(u##12,(cb)+12) SC1(u##13,(cb)+13) SC1(u##14,(cb)+14) SC1(u##15,(cb)+15) \
} while (0)

// ---------------- the scan ----------------
// grid 256 x 512 threads; wg owns TWO batch rows; streamed+prefetched weights.
__global__ __launch_bounds__(512, 2) void k_scan(
    const _Float16* __restrict__ Ph2, const _Float16* __restrict__ xh,
    const _Float16* __restrict__ w1hcQ, const _Float16* __restrict__ whhG,
    const float* __restrict__ xf, const float* __restrict__ y_hist,
    const float* __restrict__ w2g, const float* __restrict__ Wih,
    const float* __restrict__ bih, const float* __restrict__ bhh,
    const float* __restrict__ fcw, const float* __restrict__ fcb,
    const float* __restrict__ fcfw, const float* __restrict__ fcfb,
    float* __restrict__ out) {
  __shared__ __align__(16) float hc[2][512];        // fp32 [g][ h | c ]
  __shared__ __align__(16) _Float16 hcH[2][512];    // fp16 mirror for dot2
  __shared__ __align__(16) float qpart[2][2][256];  // [jk][g][e]
  __shared__ __align__(16) float Qs[2][256];        // exp(2q)
  __shared__ __align__(16) float ealpha[2][256];
  __shared__ __align__(16) float gpart[2][2][1024]; // [jk2][g][j]; aliased post-loop as cpart[2][8][256]
  __shared__ __align__(16) float w2l[256];
  __shared__ __align__(16) float Wihl[1024];
  __shared__ __align__(16) float bl[1024];
  __shared__ __align__(16) float xfL[2][256];
  __shared__ __align__(16) float yhL[2][256];
  __shared__ float redA[8], redB[8];

  const int tid = threadIdx.x;
  const int b0 = blockIdx.x * 2;
  const int hi = tid >> 8;     // 0..1 (wave-uniform)
  const int lo = tid & 255;
  const int wv = tid >> 6, lane = tid & 63;
  const int g4 = hi * 4;

  // stream base pointers
  const half8* wqp  = reinterpret_cast<const half8*>(w1hcQ) + tid;                  // [c*512]
  const half8* wgs  = reinterpret_cast<const half8*>(whhG) + (size_t)hi * 16384 + lo; // [u*256]
  const half8* prow = reinterpret_cast<const half8*>(Ph2) + ((size_t)(b0 + hi) * 32) * 256 + lo; // [c*256]

  // prefetch units
  UDECL(A); UDECL(B); UDECL(C); UDECL(D);

  // prologue: issue step-0 q weights first, then init LDS
  ULOAD(A, wqp, 512, 0);    // WQ c=0..15
  ULOAD(B, wqp, 512, 16);   // WQ c=16..31

  ((float*)hc)[tid] = 0.f;
  ((float*)hc)[tid + 512] = 0.f;
  ((_Float16*)hcH)[tid] = (_Float16)0.f;
  ((_Float16*)hcH)[tid + 512] = (_Float16)0.f;
  if (tid < 256) w2l[tid] = w2g[tid];
  Wihl[tid] = Wih[tid];
  Wihl[tid + 512] = Wih[tid + 512];
  bl[tid] = bih[tid] + bhh[tid];
  bl[tid + 512] = bih[tid + 512] + bhh[tid + 512];
  xfL[hi][lo] = xf[(size_t)(b0 + hi) * 256 + lo];
  yhL[hi][lo] = y_hist[(size_t)(b0 + hi) * 256 + lo];
  __syncthreads();

  float w2sum = 0.f;
  for (int e2 = 0; e2 < 256; ++e2) w2sum += w2l[e2];
  const float fcb0 = fcb[0];
  const float fcwy = fcw[256];

  // loop-invariant LDS pointers
  const half8* hp0 = reinterpret_cast<const half8*>(&hcH[0][hi * 256]);  // q phase
  const half8* hp1 = reinterpret_cast<const half8*>(&hcH[1][hi * 256]);
  const half8* hg0 = reinterpret_cast<const half8*>(&hcH[0][hi * 128]);  // gates
  const half8* hg1 = reinterpret_cast<const half8*>(&hcH[1][hi * 128]);
  const float4* q4 = reinterpret_cast<const float4*>(&Qs[hi][0]);        // scores
  const float4* w4 = reinterpret_cast<const float4*>(&w2l[0]);

#pragma unroll 1
  for (int s = 0; s < 256; ++s) {
    // ---- phase 1: q[e] = hc . w1_hc[e,:], k-split 2, both rows ----
    float a0 = 0.f, a1 = 0.f;
    ULOAD(C, wgs, 256, 0);    // GW u=0..15 (gates c=0..3)  -> phase 2
    QDOTS(A, 0);              // consume A (WQ c=0..15)
    ULOAD(D, wgs, 256, 16);   // GW u=16..31 (c=4..7)       -> phase 2
    QDOTS(B, 16);             // consume B (WQ c=16..31)
    qpart[hi][0][lo] = a0;
    qpart[hi][1][lo] = a1;
    __syncthreads();  // B1

    // ---- phase 2: Qs + gates GEMV h@Whh ----
    Qs[hi][lo] = __expf(2.f * (qpart[0][hi][lo] + qpart[1][hi][lo]));
    float ac00 = 0.f, ac01 = 0.f, ac02 = 0.f, ac03 = 0.f;
    float ac10 = 0.f, ac11 = 0.f, ac12 = 0.f, ac13 = 0.f;
    ULOAD(A, wgs, 256, 32);   // GW u=32..47 (c=8..11)
    GATES16(C, 0);            // consume C (c=0..3)
    ULOAD(B, wgs, 256, 48);   // GW u=48..63 (c=12..15)
    GATES16(D, 4);            // consume D
    GATES16(A, 8);            // consume A
    ULOAD(C, prow, 256, 0);   // PH c=0..15 -> phase 3
    GATES16(B, 12);           // consume B
    gpart[hi][0][lo] = ac00;
    gpart[hi][0][256 + lo] = ac01;
    gpart[hi][0][512 + lo] = ac02;
    gpart[hi][0][768 + lo] = ac03;
    gpart[hi][1][lo] = ac10;
    gpart[hi][1][256 + lo] = ac11;
    gpart[hi][1][512 + lo] = ac12;
    gpart[hi][1][768 + lo] = ac13;
    __syncthreads();  // B2

    // ---- phase 3: scores, full e-range per thread ----
    float sacc0 = 0.f, sacc1 = 0.f;
    ULOAD(D, prow, 256, 16);  // PH c=16..31
    SC16(C, 0);               // consume C
    ULOAD(A, wqp, 512, 0);    // WQ c=0..15  -> next step phase 1
    SC16(D, 16);              // consume D
    ULOAD(B, wqp, 512, 16);   // WQ c=16..31 -> next step phase 1
    {
      float sc = w2sum - 2.f * (sacc0 + sacc1);
      float ea = __expf(sc);  // no max-sub: |sc| <= ~21, fp32-safe
      ealpha[hi][lo] = ea;
      float ef = ea * xfL[hi][lo];
      float es = ea;
#pragma unroll
      for (int off = 32; off > 0; off >>= 1) {
        es += __shfl_xor(es, off);
        ef += __shfl_xor(ef, off);
      }
      if (lane == 0) { redA[wv] = es; redB[wv] = ef; }
    }
    __syncthreads();  // B3

    // ---- phase 4: softmax combine + LSTM pointwise (all threads; g = hi) ----
    {
      float es = redA[g4 + 0] + redA[g4 + 1] + redA[g4 + 2] + redA[g4 + 3];
      float ef = redB[g4 + 0] + redB[g4 + 1] + redB[g4 + 2] + redB[g4 + 3];
      float yt = ef * rcpf_(es) + fmaf(yhL[hi][s], fcwy, fcb0);
      float gi = fmaf(yt, Wihl[lo], bl[lo]);
      float gf = fmaf(yt, Wihl[256 + lo], bl[256 + lo]);
      float gc = fmaf(yt, Wihl[512 + lo], bl[512 + lo]);
      float go = fmaf(yt, Wihl[768 + lo], bl[768 + lo]);
      gi += gpart[0][hi][lo] + gpart[1][hi][lo];
      gf += gpart[0][hi][256 + lo] + gpart[1][hi][256 + lo];
      gc += gpart[0][hi][512 + lo] + gpart[1][hi][512 + lo];
      go += gpart[0][hi][768 + lo] + gpart[1][hi][768 + lo];
      float iv = sigmoidf_(gi), fv = sigmoidf_(gf), gv = tanhf_(gc), ov = sigmoidf_(go);
      float cold = hc[hi][256 + lo];
      float cn = fmaf(fv, cold, iv * gv);
      float hn = ov * tanhf_(cn);
      hc[hi][lo] = hn;
      hc[hi][256 + lo] = cn;
      hcH[hi][lo] = (_Float16)hn;
      hcH[hi][256 + lo] = (_Float16)cn;
    }
    __syncthreads();  // B4
  }

  // ---- epilogue: context from step-255 ealpha, then out = [h|ctx].fcf ----
  // read last-step softmax sums BEFORE redA/redB get reused
  const float rsA = rcpf_(redA[0] + redA[1] + redA[2] + redA[3]);
  const float rsB = rcpf_(redA[4] + redA[5] + redA[6] + redA[7]);

  float* cpartF = &gpart[0][0][0];  // alias: cpart[g][u][t] = cpartF[(g*8+u)*256+t]
  {
    const int ts = (tid >> 5) & 7;   // t-slice (32 t each)
    const int l5 = tid & 31;         // e-chunk (8 e each)
    const half8* xrow = reinterpret_cast<const half8*>(xh) +
                        ((size_t)(b0 + hi) * 256 + ts * 32) * 32 + l5;
    float acx[8];
#pragma unroll
    for (int m = 0; m < 8; ++m) acx[m] = 0.f;
#pragma unroll 4
    for (int it = 0; it < 32; ++it) {
      float al = ealpha[hi][ts * 32 + it];
      half8 xv = xrow[it * 32];
#pragma unroll
      for (int m = 0; m < 8; ++m) acx[m] = fmaf(al, (float)xv[m], acx[m]);
    }
    float* dst = &cpartF[((hi * 8 + ts) * 256) + l5 * 8];
    *reinterpret_cast<float4*>(dst) = *reinterpret_cast<float4*>(&acx[0]);
    *reinterpret_cast<float4*>(dst + 4) = *reinterpret_cast<float4*>(&acx[4]);
  }
  __syncthreads();

  {
    float cv = 0.f;
#pragma unroll
    for (int u = 0; u < 8; ++u) cv += cpartF[((hi * 8 + u) * 256) + lo];
    cv *= (hi == 0) ? rsA : rsB;
    float hval = hc[hi][lo];
    float p0 = hval * fcfw[lo] + cv * fcfw[256 + lo];
    float p1 = hval * fcfw[512 + lo] + cv * fcfw[768 + lo];
#pragma unroll
    for (int off = 32; off > 0; off >>= 1) {
      p0 += __shfl_xor(p0, off);
      p1 += __shfl_xor(p1, off);
    }
    if (lane == 0) { redA[wv] = p0; redB[wv] = p1; }
  }
  __syncthreads();
  if (tid < 4) {
    int gg = tid >> 1, o = tid & 1;
    const float* r = (o == 0) ? redA : redB;
    float v = fcfb[o] + r[gg * 4 + 0] + r[gg * 4 + 1] + r[gg * 4 + 2] + r[gg * 4 + 3];
    out[(b0 + gg) * 2 + o] = v;
  }
}

extern "C" void kernel_launch(void* const* d_in, const int* in_sizes, int n_in,
                              void* d_out, int out_size, void* d_ws, size_t ws_size,
                              hipStream_t stream) {
  (void)in_sizes; (void)n_in; (void)out_size; (void)ws_size;
  const float* x    = (const float*)d_in[0];
  const float* yh   = (const float*)d_in[1];
  const float* w1   = (const float*)d_in[2];
  const float* b1   = (const float*)d_in[3];
  const float* w2   = (const float*)d_in[4];
  /* d_in[5] attn_b2: softmax-invariant, unused */
  const float* Wih  = (const float*)d_in[6];
  const float* Whh  = (const float*)d_in[7];
  const float* bih  = (const float*)d_in[8];
  const float* bhh  = (const float*)d_in[9];
  const float* fcw  = (const float*)d_in[10];
  const float* fcb  = (const float*)d_in[11];
  const float* fcfw = (const float*)d_in[12];
  const float* fcfb = (const float*)d_in[13];
  float* out = (float*)d_out;

  char* ws = (char*)d_ws;
  _Float16* Ph2   = (_Float16*)(ws);                      // 67108864 B
  _Float16* xh    = (_Float16*)(ws + (size_t)67108864);   // 67108864 B
  float*    wT    = (float*)   (ws + (size_t)134217728);  // 262144 B
  _Float16* w1hcQ = (_Float16*)(ws + (size_t)134479872);  // 262144 B
  _Float16* whhG  = (_Float16*)(ws + (size_t)134742016);  // 524288 B
  float*    xf    = (float*)   (ws + (size_t)135266304);  // 524288 B
  // total: 135790592 B (~129.5 MB)

  k_prep_wT   <<<256,   256, 0, stream>>>(w1, wT);
  k_prep_xh   <<<32768, 256, 0, stream>>>(x, xh);
  k_prep_w1hcQ<<<512,   256, 0, stream>>>(w1, w1hcQ);
  k_prep_whhG <<<1024,  256, 0, stream>>>(Whh, whhG);
  k_xf        <<<8192,  256, 0, stream>>>(x, fcw, xf);
  k_encp      <<<8192,  256, 0, stream>>>(x, wT, b1, Ph2);
  k_scan      <<<256,   512, 0, stream>>>(Ph2, xh, w1hcQ, whhG, xf, yh, w2, Wih,
                                          bih, bhh, fcw, fcb, fcfw, fcfb, out);
}

// Round 6
// 5072.794 us; speedup vs baseline: 6.3988x; 6.3988x over previous
//
#include <hip/hip_runtime.h>
#include <cstdint>
#include <cstddef>

// Decoder (DA-RNN): B=512, T=256, E=D=256.
// Round 8: back to the verified-best R1 geometry (256 blocks x 1024 threads,
// 2 rows/block, streamed weights, 5 barriers/step, 5459us) with its ONE
// measured defect fixed: phase-1 used jk=tid&3, putting 4 lanes at addresses
// 256B apart -> 4-way same-bank conflict on every h-read + conflicted qpart
// writes (SQ_LDS_BANK_CONFLICT=4.15e8, ~13% of cycles). Phase 1 now splits k
// via jk=tid>>8 (wave-uniform): h-reads become same-address broadcasts (free),
// qpart writes lane-consecutive (free). w1hcQ layout matches the new mapping.
// Register-prefetch approaches are dead: R3/R4/R5 all spilled (VGPR cap 128,
// WRITE_SIZE 137-317MB). Streaming + TLP is the working regime.

typedef _Float16 half8 __attribute__((ext_vector_type(8)));
typedef _Float16 half4v __attribute__((ext_vector_type(4)));
typedef _Float16 half2v __attribute__((ext_vector_type(2)));

__device__ __forceinline__ float rcpf_(float x) { return __builtin_amdgcn_rcpf(x); }
__device__ __forceinline__ float sigmoidf_(float x) { return rcpf_(1.f + __expf(-x)); }
__device__ __forceinline__ float tanhf_(float x) { return 1.f - 2.f * rcpf_(1.f + __expf(2.f * x)); }

#if defined(__has_builtin)
#if __has_builtin(__builtin_amdgcn_fdot2)
#define HAS_FDOT2 1
#endif
#endif
#ifndef HAS_FDOT2
#define HAS_FDOT2 0
#endif

__device__ __forceinline__ float fdot2_(half2v a, half2v b, float c) {
#if HAS_FDOT2
  return __builtin_amdgcn_fdot2(a, b, c, false);
#else
  return fmaf((float)a[0], (float)b[0], fmaf((float)a[1], (float)b[1], c));
#endif
}

__device__ __forceinline__ float dot8_(half8 w, half8 h, float acc) {
  acc = fdot2_(__builtin_shufflevector(w, w, 0, 1), __builtin_shufflevector(h, h, 0, 1), acc);
  acc = fdot2_(__builtin_shufflevector(w, w, 2, 3), __builtin_shufflevector(h, h, 2, 3), acc);
  acc = fdot2_(__builtin_shufflevector(w, w, 4, 5), __builtin_shufflevector(h, h, 4, 5), acc);
  acc = fdot2_(__builtin_shufflevector(w, w, 6, 7), __builtin_shufflevector(h, h, 6, 7), acc);
  return acc;
}

// ---------------- prep kernels ----------------

// wT[e*256+f] = attn_w1[f*768 + 512 + e]   (transposed w1_enc, fp32)
__global__ void k_prep_wT(const float* __restrict__ w1, float* __restrict__ wT) {
  int id = blockIdx.x * 256 + threadIdx.x;
  int e = id >> 8, f = id & 255;
  wT[id] = w1[f * 768 + 512 + e];
}

// x -> fp16 (4 elems/thread), layout unchanged [b][t][e]
__global__ void k_prep_xh(const float* __restrict__ x, _Float16* __restrict__ xh) {
  int id = blockIdx.x * 256 + threadIdx.x;
  float4 v = reinterpret_cast<const float4*>(x)[id];
  half4v h;
  h[0] = (_Float16)v.x; h[1] = (_Float16)v.y; h[2] = (_Float16)v.z; h[3] = (_Float16)v.w;
  reinterpret_cast<half4v*>(xh)[id] = h;
}

// w1hcQ[(c*1024 + t)*8 + m] = w1[e*768 + k],  t = jk*256 + e  (jk = t>>8
// wave-uniform in k_scan), k = jk*128 + c*8 + m, c in [0,16)
__global__ void k_prep_w1hcQ(const float* __restrict__ w1, _Float16* __restrict__ o) {
  int id = blockIdx.x * 256 + threadIdx.x;  // 131072 total
  int m = id & 7, t = (id >> 3) & 1023, c = id >> 13;
  int e = t & 255, jk = t >> 8;
  int k = jk * 128 + c * 8 + m;
  o[id] = (_Float16)w1[e * 768 + k];
}

// whhG[(((jk*8 + c)*4 + jslot)*256 + jo)*8 + m] = Whh[(jslot*256+jo)*256 + jk*64 + c*8 + m]
// (thread (jo, jk=tid>>8) computes 4 outputs jslot*256+jo over k in [jk*64,+64))
__global__ void k_prep_whhG(const float* __restrict__ whh, _Float16* __restrict__ o) {
  int id = blockIdx.x * 256 + threadIdx.x;  // 262144 total
  int m = id & 7, jo = (id >> 3) & 255, jslot = (id >> 11) & 3;
  int c = (id >> 13) & 7, jk = id >> 16;
  int j = jslot * 256 + jo, k = jk * 64 + c * 8 + m;
  o[id] = (_Float16)whh[j * 256 + k];
}

// xf[b*256+t] = sum_e x[b,t,e] * fcw[e]   (fp32)
__global__ __launch_bounds__(256) void k_xf(const float* __restrict__ x,
                                            const float* __restrict__ fcw,
                                            float* __restrict__ xf) {
  __shared__ float xl[16][256];
  __shared__ float fw[256];
  __shared__ float part[16][17];
  const int tid = threadIdx.x;
  const int m0 = blockIdx.x * 16;
  fw[tid] = fcw[tid];
#pragma unroll
  for (int r = 0; r < 16; ++r) xl[r][tid] = x[(size_t)(m0 + r) * 256 + tid];
  __syncthreads();
  int r = tid >> 4, p = tid & 15;
  float s = 0.f;
#pragma unroll
  for (int u = 0; u < 16; ++u) s = fmaf(xl[r][p * 16 + u], fw[p * 16 + u], s);
  part[r][p] = s;
  __syncthreads();
  if (tid < 16) {
    float t = 0.f;
#pragma unroll
    for (int p2 = 0; p2 < 16; ++p2) t += part[tid][p2];
    xf[m0 + tid] = t;
  }
}

// enc_proj GEMM + bias, store P=exp(2*encp) fp16 in layout [b][e/8][t][e%8]
__global__ __launch_bounds__(256) void k_encp(const float* __restrict__ x,
                                              const float* __restrict__ wT,
                                              const float* __restrict__ b1,
                                              _Float16* __restrict__ Ph2) {
  __shared__ __align__(16) float xl[16][256];
  const int tid = threadIdx.x;
  const int m0 = blockIdx.x * 16;
#pragma unroll
  for (int r = 0; r < 16; ++r) xl[r][tid] = x[(size_t)(m0 + r) * 256 + tid];
  __syncthreads();
  float acc[16];
#pragma unroll
  for (int r = 0; r < 16; ++r) acc[r] = 0.f;
  for (int e = 0; e < 256; e += 4) {
    float w0 = wT[(e + 0) * 256 + tid];
    float w1_ = wT[(e + 1) * 256 + tid];
    float w2_ = wT[(e + 2) * 256 + tid];
    float w3_ = wT[(e + 3) * 256 + tid];
#pragma unroll
    for (int r = 0; r < 16; ++r) {
      float4 xv = *reinterpret_cast<const float4*>(&xl[r][e]);
      acc[r] = fmaf(xv.x, w0, acc[r]);
      acc[r] = fmaf(xv.y, w1_, acc[r]);
      acc[r] = fmaf(xv.z, w2_, acc[r]);
      acc[r] = fmaf(xv.w, w3_, acc[r]);
    }
  }
  float bb = b1[tid];
  const int e = tid;
#pragma unroll
  for (int r = 0; r < 16; ++r) {
    int m = m0 + r, b = m >> 8, t = m & 255;
    float p = __expf(2.f * (acc[r] + bb));
    Ph2[((size_t)(b * 32 + (e >> 3)) * 256 + t) * 8 + (e & 7)] = (_Float16)p;
  }
}

// ---------------- the scan ----------------
// grid 256 x 1024 threads; wg owns 2 batch rows; 256 steps; 16 waves/CU.
__global__ __launch_bounds__(1024, 4) void k_scan(
    const _Float16* __restrict__ Ph2, const _Float16* __restrict__ xh,
    const _Float16* __restrict__ w1hcQ, const _Float16* __restrict__ whhG,
    const float* __restrict__ xf, const float* __restrict__ y_hist,
    const float* __restrict__ w2g, const float* __restrict__ Wih,
    const float* __restrict__ bih, const float* __restrict__ bhh,
    const float* __restrict__ fcw, const float* __restrict__ fcb,
    const float* __restrict__ fcfw, const float* __restrict__ fcfb,
    float* __restrict__ out) {
  __shared__ __align__(16) float hc[2][512];        // fp32 [g][ h | c ]
  __shared__ __align__(16) _Float16 hcH[2][512];    // fp16 mirror for dot2
  __shared__ __align__(16) float qpart[4][2][256];  // [jk][g][e]
  __shared__ __align__(16) float Qs[2][256];        // exp(2q)
  __shared__ __align__(16) float spart[2][2][256];  // [eh][g][t]
  __shared__ __align__(16) float ealpha[2][256];
  __shared__ __align__(16) float gpart[4][2][1024]; // [jk][g][j]; aliased post-loop as cpart[2][16][256]
  __shared__ __align__(16) float w2l[256];
  __shared__ __align__(16) float Wihl[1024];
  __shared__ __align__(16) float bl[1024];
  __shared__ __align__(16) float xfL[2][256];
  __shared__ __align__(16) float yhL[2][256];
  __shared__ float redA[8], redB[8];

  const int tid = threadIdx.x;
  const int b0 = blockIdx.x * 2;
  const int hi = tid >> 8;     // 0..3, wave-uniform
  const int lo = tid & 255;
  const int wv = tid >> 6, lane = tid & 63;

  // ---- init ----
  ((float*)hc)[tid] = 0.f;
  ((_Float16*)hcH)[tid] = (_Float16)0.f;
  if (tid < 256) w2l[tid] = w2g[tid];
  Wihl[tid & 1023] = Wih[tid & 1023];
  bl[tid] = bih[tid] + bhh[tid];
  if (tid < 512) {
    int gi = tid >> 8, ti = tid & 255;
    xfL[gi][ti] = xf[(size_t)(b0 + gi) * 256 + ti];
    yhL[gi][ti] = y_hist[(size_t)(b0 + gi) * 256 + ti];
  }
  __syncthreads();
  float w2sum = 0.f;
  for (int e2 = 0; e2 < 256; ++e2) w2sum += w2l[e2];
  const float fcb0 = fcb[0];
  const float fcwy = fcw[256];

  // per-thread role constants
  // q phase: thread = (jk = hi, e = lo), k in [jk*128, +128)  [wave-uniform jk]
  const half8* wq = reinterpret_cast<const half8*>(w1hcQ) + tid;  // chunk c: wq[c*1024]
  // gates: thread = (jo = lo, jk = hi); outputs jslot*256+jo, k in [jk*64, +64)
  const half8* wg = reinterpret_cast<const half8*>(whhG) + (size_t)hi * 8192 + lo;
  // scores: thread = (g = tid>>9, eh = (tid>>8)&1, t = lo), e in [eh*128, +128)
  const int gs = tid >> 9, eh = (tid >> 8) & 1;
  const half8* prow = reinterpret_cast<const half8*>(Ph2) +
                      ((size_t)((b0 + gs) * 32 + eh * 16)) * 256 + lo;
  // pointwise / softmax-combine (tid < 512)
  const int gp = (tid >> 8) & 1;

#pragma unroll 1
  for (int s = 0; s < 256; ++s) {
    // ---- phase 1: q[e] = hc . w1_hc[e,:], k-split 4 (wave-uniform), both rows ----
    float a0 = 0.f, a1 = 0.f;
    {
      const half8* hp0 = reinterpret_cast<const half8*>(&hcH[0][hi * 128]);
      const half8* hp1 = reinterpret_cast<const half8*>(&hcH[1][hi * 128]);
#pragma unroll 8
      for (int c = 0; c < 16; ++c) {
        half8 w = wq[c * 1024];
        half8 h0 = hp0[c];   // broadcast read (same addr across wave)
        half8 h1 = hp1[c];
        a0 = dot8_(w, h0, a0);
        a1 = dot8_(w, h1, a1);
      }
    }
    qpart[hi][0][lo] = a0;
    qpart[hi][1][lo] = a1;
    __syncthreads();  // B1

    // ---- phase 2: Qs (tid<512) + gates GEMV h@Whh (all threads, both rows) ----
    if (tid < 512) {
      float qv = qpart[0][gp][lo] + qpart[1][gp][lo] + qpart[2][gp][lo] + qpart[3][gp][lo];
      Qs[gp][lo] = __expf(2.f * qv);
    }
    float ac0[4], ac1[4];
#pragma unroll
    for (int m = 0; m < 4; ++m) { ac0[m] = 0.f; ac1[m] = 0.f; }
    {
      const half8* hg0 = reinterpret_cast<const half8*>(&hcH[0][hi * 64]);
      const half8* hg1 = reinterpret_cast<const half8*>(&hcH[1][hi * 64]);
#pragma unroll 2
      for (int c = 0; c < 8; ++c) {
        half8 h0 = hg0[c];   // broadcast
        half8 h1 = hg1[c];
#pragma unroll
        for (int jslot = 0; jslot < 4; ++jslot) {
          half8 w = wg[(c * 4 + jslot) * 256];
          ac0[jslot] = dot8_(w, h0, ac0[jslot]);
          ac1[jslot] = dot8_(w, h1, ac1[jslot]);
        }
      }
    }
#pragma unroll
    for (int jslot = 0; jslot < 4; ++jslot) {
      gpart[hi][0][jslot * 256 + lo] = ac0[jslot];
      gpart[hi][1][jslot * 256 + lo] = ac1[jslot];
    }
    __syncthreads();  // B2

    // ---- phase 3: scores, e-split 2: sacc = sum_e w2[e]/(P*Q+1) ----
    float sacc0 = 0.f, sacc1 = 0.f;
    {
      const float4* q4 = reinterpret_cast<const float4*>(&Qs[gs][eh * 128]);
      const float4* w4 = reinterpret_cast<const float4*>(&w2l[eh * 128]);
#pragma unroll 8
      for (int c = 0; c < 16; ++c) {
        half8 pv = __builtin_nontemporal_load(prow + c * 256);
        float4 qa = q4[2 * c], qb = q4[2 * c + 1];
        float4 wa = w4[2 * c], wb = w4[2 * c + 1];
        sacc0 = fmaf(wa.x, rcpf_(fmaf((float)pv[0], qa.x, 1.f)), sacc0);
        sacc1 = fmaf(wa.y, rcpf_(fmaf((float)pv[1], qa.y, 1.f)), sacc1);
        sacc0 = fmaf(wa.z, rcpf_(fmaf((float)pv[2], qa.z, 1.f)), sacc0);
        sacc1 = fmaf(wa.w, rcpf_(fmaf((float)pv[3], qa.w, 1.f)), sacc1);
        sacc0 = fmaf(wb.x, rcpf_(fmaf((float)pv[4], qb.x, 1.f)), sacc0);
        sacc1 = fmaf(wb.y, rcpf_(fmaf((float)pv[5], qb.y, 1.f)), sacc1);
        sacc0 = fmaf(wb.z, rcpf_(fmaf((float)pv[6], qb.z, 1.f)), sacc0);
        sacc1 = fmaf(wb.w, rcpf_(fmaf((float)pv[7], qb.w, 1.f)), sacc1);
      }
    }
    spart[eh][gs][lo] = sacc0 + sacc1;
    __syncthreads();  // B3

    // ---- phase 4: combine + softmax reduce (tid < 512) ----
    if (tid < 512) {
      float sc = w2sum - 2.f * (spart[0][gp][lo] + spart[1][gp][lo]);
      float ea = __expf(sc);  // no max-sub: |sc| <= ~21, fp32-safe
      ealpha[gp][lo] = ea;
      float ef = ea * xfL[gp][lo];
      float es = ea;
#pragma unroll
      for (int off = 32; off > 0; off >>= 1) {
        es += __shfl_xor(es, off);
        ef += __shfl_xor(ef, off);
      }
      if (lane == 0) { redA[wv] = es; redB[wv] = ef; }
    }
    __syncthreads();  // B4

    // ---- phase 5: LSTM pointwise (tid < 512) ----
    if (tid < 512) {
      float es = (gp == 0) ? (redA[0] + redA[1] + redA[2] + redA[3])
                           : (redA[4] + redA[5] + redA[6] + redA[7]);
      float ef = (gp == 0) ? (redB[0] + redB[1] + redB[2] + redB[3])
                           : (redB[4] + redB[5] + redB[6] + redB[7]);
      float yt = ef * rcpf_(es) + fmaf(yhL[gp][s], fcwy, fcb0);
      float gi = fmaf(yt, Wihl[lo], bl[lo]);
      float gf = fmaf(yt, Wihl[256 + lo], bl[256 + lo]);
      float gc = fmaf(yt, Wihl[512 + lo], bl[512 + lo]);
      float go = fmaf(yt, Wihl[768 + lo], bl[768 + lo]);
#pragma unroll
      for (int q2 = 0; q2 < 4; ++q2) {
        gi += gpart[q2][gp][lo];
        gf += gpart[q2][gp][256 + lo];
        gc += gpart[q2][gp][512 + lo];
        go += gpart[q2][gp][768 + lo];
      }
      float iv = sigmoidf_(gi), fv = sigmoidf_(gf), gv = tanhf_(gc), ov = sigmoidf_(go);
      float cold = hc[gp][256 + lo];
      float cn = fmaf(fv, cold, iv * gv);
      float hn = ov * tanhf_(cn);
      hc[gp][lo] = hn;
      hc[gp][256 + lo] = cn;
      hcH[gp][lo] = (_Float16)hn;
      hcH[gp][256 + lo] = (_Float16)cn;
    }
    __syncthreads();  // B5
  }

  // ---- epilogue: context from step-255 ealpha, then out = [h|ctx].fcf ----
  // read last-step softmax sums BEFORE redA/redB get reused
  const float rsA = rcpf_(redA[0] + redA[1] + redA[2] + redA[3]);
  const float rsB = rcpf_(redA[4] + redA[5] + redA[6] + redA[7]);

  float* cpartF = &gpart[0][0][0];  // alias: cpart[g][u][t] = cpartF[(g*16+u)*256+t]
  {
    const int gc = tid >> 9, t16 = (tid >> 5) & 15, l5 = tid & 31;
    const half8* xrow = reinterpret_cast<const half8*>(xh) +
                        ((size_t)(b0 + gc) * 256 + t16 * 16) * 32 + l5;
    float acx[8];
#pragma unroll
    for (int m = 0; m < 8; ++m) acx[m] = 0.f;
#pragma unroll 4
    for (int it = 0; it < 16; ++it) {
      float al = ealpha[gc][t16 * 16 + it];
      half8 xv = xrow[it * 32];
#pragma unroll
      for (int m = 0; m < 8; ++m) acx[m] = fmaf(al, (float)xv[m], acx[m]);
    }
    float* dst = &cpartF[((gc * 16 + t16) * 256) + l5 * 8];
    *reinterpret_cast<float4*>(dst) = *reinterpret_cast<float4*>(&acx[0]);
    *reinterpret_cast<float4*>(dst + 4) = *reinterpret_cast<float4*>(&acx[4]);
  }
  __syncthreads();

  if (tid < 512) {
    float cv = 0.f;
#pragma unroll
    for (int u = 0; u < 16; ++u) cv += cpartF[((gp * 16 + u) * 256) + lo];
    cv *= (gp == 0) ? rsA : rsB;
    float hval = hc[gp][lo];
    float p0 = hval * fcfw[lo] + cv * fcfw[256 + lo];
    float p1 = hval * fcfw[512 + lo] + cv * fcfw[768 + lo];
#pragma unroll
    for (int off = 32; off > 0; off >>= 1) {
      p0 += __shfl_xor(p0, off);
      p1 += __shfl_xor(p1, off);
    }
    if (lane == 0) { redA[wv] = p0; redB[wv] = p1; }
  }
  __syncthreads();
  if (tid < 4) {
    int g2 = tid >> 1, o = tid & 1;
    const float* r = (o == 0) ? redA : redB;
    float v = fcfb[o] + r[g2 * 4 + 0] + r[g2 * 4 + 1] + r[g2 * 4 + 2] + r[g2 * 4 + 3];
    out[(b0 + g2) * 2 + o] = v;
  }
}

extern "C" void kernel_launch(void* const* d_in, const int* in_sizes, int n_in,
                              void* d_out, int out_size, void* d_ws, size_t ws_size,
                              hipStream_t stream) {
  (void)in_sizes; (void)n_in; (void)out_size; (void)ws_size;
  const float* x    = (const float*)d_in[0];
  const float* yh   = (const float*)d_in[1];
  const float* w1   = (const float*)d_in[2];
  const float* b1   = (const float*)d_in[3];
  const float* w2   = (const float*)d_in[4];
  /* d_in[5] attn_b2: softmax-invariant, unused */
  const float* Wih  = (const float*)d_in[6];
  const float* Whh  = (const float*)d_in[7];
  const float* bih  = (const float*)d_in[8];
  const float* bhh  = (const float*)d_in[9];
  const float* fcw  = (const float*)d_in[10];
  const float* fcb  = (const float*)d_in[11];
  const float* fcfw = (const float*)d_in[12];
  const float* fcfb = (const float*)d_in[13];
  float* out = (float*)d_out;

  char* ws = (char*)d_ws;
  _Float16* Ph2   = (_Float16*)(ws);                      // 67108864 B
  _Float16* xh    = (_Float16*)(ws + (size_t)67108864);   // 67108864 B
  float*    wT    = (float*)   (ws + (size_t)134217728);  // 262144 B
  _Float16* w1hcQ = (_Float16*)(ws + (size_t)134479872);  // 262144 B
  _Float16* whhG  = (_Float16*)(ws + (size_t)134742016);  // 524288 B
  float*    xf    = (float*)   (ws + (size_t)135266304);  // 524288 B
  // total: 135790592 B (~129.5 MB)

  k_prep_wT   <<<256,   256, 0, stream>>>(w1, wT);
  k_prep_xh   <<<32768, 256, 0, stream>>>(x, xh);
  k_prep_w1hcQ<<<512,   256, 0, stream>>>(w1, w1hcQ);
  k_prep_whhG <<<1024,  256, 0, stream>>>(Whh, whhG);
  k_xf        <<<8192,  256, 0, stream>>>(x, fcw, xf);
  k_encp      <<<8192,  256, 0, stream>>>(x, wT, b1, Ph2);
  k_scan      <<<256,  1024, 0, stream>>>(Ph2, xh, w1hcQ, whhG, xf, yh, w2, Wih,
                                          bih, bhh, fcw, fcb, fcfw, fcfb, out);
}